// Round 13
// baseline (201.533 us; speedup 1.0000x reference)
//
#include <hip/hip_runtime.h>
#include <cstdint>

#define D_MODEL 1024
#define HIDDEN  4096
#define BATCH   4
#define SEQ     2048
#define NROWS   (BATCH*SEQ)   // 8192

typedef __attribute__((ext_vector_type(4))) int i32x4;

#define ACT_AMAX 4.0f
#define ACT_S    (ACT_AMAX / 127.0f)
#define ACT_INV  (127.0f / ACT_AMAX)

#define GLDS16(g, l) __builtin_amdgcn_global_load_lds(                        \
    (const __attribute__((address_space(1))) unsigned int*)(g),               \
    (__attribute__((address_space(3))) unsigned int*)(l), 16, 0, 0)

__device__ __forceinline__ float block_sum(float v, float* s4) {
  #pragma unroll
  for (int off = 32; off > 0; off >>= 1) v += __shfl_down(v, off);
  int lane = threadIdx.x & 63, wid = threadIdx.x >> 6;
  __syncthreads();
  if (lane == 0) s4[wid] = v;
  __syncthreads();
  return s4[0] + s4[1] + s4[2] + s4[3];
}

__device__ __forceinline__ float block_max(float v, float* s4) {
  #pragma unroll
  for (int off = 32; off > 0; off >>= 1) v = fmaxf(v, __shfl_down(v, off));
  int lane = threadIdx.x & 63, wid = threadIdx.x >> 6;
  __syncthreads();
  if (lane == 0) s4[wid] = v;
  __syncthreads();
  return fmaxf(fmaxf(s4[0], s4[1]), fmaxf(s4[2], s4[3]));
}

__device__ __forceinline__ signed char qclamp(float v) {
  float r = rintf(v);
  r = fminf(127.f, fmaxf(-127.f, r));
  return (signed char)(int)r;
}

// ---- per-column absmax of W [R][C] -> u32-encoded f32 maxima ----
__global__ __launch_bounds__(256) void absmax_cols(
    const float* __restrict__ in, int R, int C, unsigned* __restrict__ u) {
  int c  = blockIdx.x * 256 + threadIdx.x;
  int r0 = blockIdx.y * 64;
  float m = 0.f;
  #pragma unroll 4
  for (int r = 0; r < 64; ++r)
    m = fmaxf(m, fabsf(in[(size_t)(r0 + r) * C + c]));
  atomicMax(&u[c], __float_as_uint(m));   // non-negative f32: uint order == f32 order
}

// ---- transpose + quantize: in [R][C] f32 -> out [C][R] i8; inv from u32 absmax ----
__global__ __launch_bounds__(256) void transpose_quant(
    const float* __restrict__ in, signed char* __restrict__ out,
    int R, int C, const unsigned* __restrict__ u) {
  __shared__ float tile[32][33];
  int c0 = blockIdx.x * 32, r0 = blockIdx.y * 32;
  int tx = threadIdx.x & 31, ty = threadIdx.x >> 5;
  #pragma unroll
  for (int i = ty; i < 32; i += 8)
    tile[i][tx] = in[(size_t)(r0 + i) * C + c0 + tx];
  __syncthreads();
  #pragma unroll
  for (int i = ty; i < 32; i += 8) {
    float f = __uint_as_float(u[c0 + i]);
    float inv = f > 0.f ? 127.f / f : 0.f;
    out[(size_t)(c0 + i) * R + r0 + tx] = qclamp(tile[tx][i] * inv);
  }
}

// ---- fused LN1(row0 of each batch) + split-K matvec; atomicAdd into vout ----
#define KCHUNKS 32
#define KCH     (D_MODEL / KCHUNKS)   // 32
__global__ __launch_bounds__(256) void ln_matvec_split(
    const float* __restrict__ x, const float* __restrict__ ln_a,
    const float* __restrict__ ln_b, const float* __restrict__ W,
    float* __restrict__ vout) {
  __shared__ float s4[4];
  __shared__ float hs[4][KCH];
  int n  = blockIdx.x * 256 + threadIdx.x;
  int k0 = blockIdx.y * KCH;
  int t  = threadIdx.x;
  float4 g4 = ((const float4*)ln_a)[t];
  float4 b4 = ((const float4*)ln_b)[t];
  #pragma unroll
  for (int b = 0; b < 4; ++b) {
    const float* xr = x + (size_t)b * SEQ * D_MODEL;
    float4 v = ((const float4*)xr)[t];          // cols 4t..4t+3
    float sum = v.x + v.y + v.z + v.w;
    float mean = block_sum(sum, s4) * (1.f / 1024.f);
    float cx = v.x - mean, cy = v.y - mean, cz = v.z - mean, cw = v.w - mean;
    float sq = cx * cx + cy * cy + cz * cz + cw * cw;
    float var = block_sum(sq, s4) * (1.f / 1023.f);   // ddof=1
    float inv = 1.f / (sqrtf(var) + 1e-6f);           // eps on std
    if (t >= (k0 >> 2) && t < ((k0 + KCH) >> 2)) {    // keep our k-chunk
      int lc = 4 * t - k0;
      hs[b][lc + 0] = g4.x * cx * inv + b4.x;
      hs[b][lc + 1] = g4.y * cy * inv + b4.y;
      hs[b][lc + 2] = g4.z * cz * inv + b4.z;
      hs[b][lc + 3] = g4.w * cw * inv + b4.w;
    }
  }
  __syncthreads();
  float a0 = 0, a1 = 0, a2 = 0, a3 = 0;
  #pragma unroll
  for (int k = 0; k < KCH; ++k) {
    float w = W[(size_t)(k0 + k) * D_MODEL + n];
    a0 = fmaf(hs[0][k], w, a0);
    a1 = fmaf(hs[1][k], w, a1);
    a2 = fmaf(hs[2][k], w, a2);
    a3 = fmaf(hs[3][k], w, a3);
  }
  atomicAdd(&vout[0 * D_MODEL + n], a0);
  atomicAdd(&vout[1 * D_MODEL + n], a1);
  atomicAdd(&vout[2 * D_MODEL + n], a2);
  atomicAdd(&vout[3 * D_MODEL + n], a3);
}

// ---- split-K matvec (vin [4][D] dense), atomicAdd into vout ----
__global__ __launch_bounds__(256) void matvec_split_atomic(
    const float* __restrict__ vin, const float* __restrict__ W,
    float* __restrict__ vout) {
  __shared__ float hs[4][KCH];
  int n  = blockIdx.x * 256 + threadIdx.x;
  int k0 = blockIdx.y * KCH;
  if (threadIdx.x < 4 * KCH)
    hs[threadIdx.x / KCH][threadIdx.x % KCH] =
        vin[(threadIdx.x / KCH) * D_MODEL + k0 + (threadIdx.x % KCH)];
  __syncthreads();
  float a0 = 0, a1 = 0, a2 = 0, a3 = 0;
  #pragma unroll
  for (int k = 0; k < KCH; ++k) {
    float w = W[(size_t)(k0 + k) * D_MODEL + n];
    a0 = fmaf(hs[0][k], w, a0);
    a1 = fmaf(hs[1][k], w, a1);
    a2 = fmaf(hs[2][k], w, a2);
    a3 = fmaf(hs[3][k], w, a3);
  }
  atomicAdd(&vout[0 * D_MODEL + n], a0);
  atomicAdd(&vout[1 * D_MODEL + n], a1);
  atomicAdd(&vout[2 * D_MODEL + n], a2);
  atomicAdd(&vout[3 * D_MODEL + n], a3);
}

// ---- x1 = x + delta[b] -> out (f32); LN2 -> h2 (i8, per-row scale hs) ----
__global__ __launch_bounds__(256) void fused_res_ln_q(
    const float* __restrict__ x, const float* __restrict__ delta,
    const float* __restrict__ g, const float* __restrict__ be,
    float* __restrict__ x1_out, signed char* __restrict__ h2,
    float* __restrict__ hscale) {
  __shared__ float s4[4];
  int row = blockIdx.x;
  int b = row >> 11;                 // row / SEQ
  int t = threadIdx.x;
  float4 v  = ((const float4*)(x + (size_t)row * D_MODEL))[t];
  float4 d4 = ((const float4*)(delta + (size_t)b * D_MODEL))[t];
  v.x += d4.x; v.y += d4.y; v.z += d4.z; v.w += d4.w;
  float sum = v.x + v.y + v.z + v.w;
  float mean = block_sum(sum, s4) * (1.f / 1024.f);
  float cx = v.x - mean, cy = v.y - mean, cz = v.z - mean, cw = v.w - mean;
  float sq = cx * cx + cy * cy + cz * cz + cw * cw;
  float var = block_sum(sq, s4) * (1.f / 1023.f);   // ddof=1
  float inv = 1.f / (sqrtf(var) + 1e-6f);           // eps on std
  ((float4*)(x1_out + (size_t)row * D_MODEL))[t] = v;
  float4 g4 = ((const float4*)g)[t];
  float4 b4 = ((const float4*)be)[t];
  float h0v = g4.x * cx * inv + b4.x;
  float h1v = g4.y * cy * inv + b4.y;
  float h2v = g4.z * cz * inv + b4.z;
  float h3v = g4.w * cw * inv + b4.w;
  float am = fmaxf(fmaxf(fabsf(h0v), fabsf(h1v)), fmaxf(fabsf(h2v), fabsf(h3v)));
  float amax = block_max(am, s4);
  float qs = amax > 0.f ? 127.f / amax : 0.f;
  unsigned q = ((unsigned)(unsigned char)(int)qclamp(h0v * qs)) |
               ((unsigned)(unsigned char)(int)qclamp(h1v * qs) << 8) |
               ((unsigned)(unsigned char)(int)qclamp(h2v * qs) << 16) |
               ((unsigned)(unsigned char)(int)qclamp(h3v * qs) << 24);
  ((unsigned*)(h2 + (size_t)row * D_MODEL))[t] = q;
  if (t == 0) hscale[row] = amax * (1.f / 127.f);
}

// ============================================================================
// int8 128x128-tile GEMM, K-step 128, mfma_i32_16x16x64_i8, 4 waves (2Mx2N),
// 256 thr, single 32 KB LDS buffer.  MW = min-waves/EU (= blocks/CU here).
// R11 lesson: a source-level kk-slice does NOT cap the operand live-set --
// the compiler hoists the second slice's ds_reads up (no fence), restoring
// the 64-reg window and spilling at MW=4.  Fix: sched_barrier(0) between
// the two {RD, 16xMFMA} slices -- nothing crosses, operand window = 32 regs,
// live across fence = acc(64)+addr (~116 < 128 budget at MW=4).
// Within-round A/B: GEMM1 runs MW=4 (experiment), GEMM2 runs MW=3 (proven).
// Spill tripwire: GEMM1 VGPR < 90 or WRITE_SIZE > 40 MB -> revert next round.
// Per tile: {STG (8 gload_lds) -> vmcnt(0) -> bar -> [RD MM SBAR]x2 -> bar}.
// LDS rows 128 B, source col pre-swizzled, reads XOR (lr&7)<<4 -> 0 conflicts.
// EPI 0: dequant+bias+gelu -> i8 act.
// EPI 1: dequant(+bias if ks==0) -> add into Cf (KS=1: plain RMW; KS>1: atomic).
// ============================================================================
template <int EPI, int KS, int MW>
__global__ __launch_bounds__(256, MW) void gemm_i8(
    const signed char* __restrict__ A, const signed char* __restrict__ Bt,
    const float* __restrict__ rowS, float rowConst,
    const unsigned* __restrict__ colU, const float* __restrict__ bias,
    signed char* __restrict__ Cq, float* __restrict__ Cf, int M, int N, int K) {
  __shared__ signed char LA[128][128];   // 16 KB
  __shared__ signed char LB[128][128];   // 16 KB

  int GN  = N / 128;
  int PS  = (M / 128) * GN;          // blocks per k-slice
  int nwg = PS * KS;
  int id  = blockIdx.x;
  int sw  = (id & 7) * (nwg >> 3) + (id >> 3);      // XCD-aware swizzle
  int ks  = sw / PS, rem = sw % PS;
  int by  = rem / GN, bx = rem % GN;
  int m0  = by * 128, n0 = bx * 128;
  int KSL = K / KS;                  // K per slice
  int k0s = ks * KSL;
  int NT  = KSL / 128;               // K-tiles (128 i8 per step)

  int t = threadIdx.x;
  int wid = t >> 6, lane = t & 63;
  int wm = wid >> 1, wn = wid & 1;   // wave grid 2M x 2N, 64x64 per wave
  int lr = lane & 15, kg = lane >> 4;
  int swz = (lr & 7) << 4;           // read-side XOR (bytes)

  // staging: row = t>>3 (8 thr x 16B = one 128B row), pre-swizzled source col
  int rS = t >> 3;                   // 0..31
  int cS = ((t & 7) ^ (rS & 7)) * 16;
  const signed char* Ag = A  + (size_t)(m0 + rS) * K + k0s + cS;
  const signed char* Bg = Bt + (size_t)(n0 + rS) * K + k0s + cS;
  int ldsOff = wid * 1024;           // wave-uniform; lane*16B added by HW

#define STG_T(T) do {                                                          \
    size_t ko_ = (size_t)(T) * 128;                                            \
    GLDS16(Ag + ko_,                  &LA[0][0] + ldsOff);                     \
    GLDS16(Ag + ko_ + (size_t)32 * K, &LA[0][0] + ldsOff + 4096);              \
    GLDS16(Ag + ko_ + (size_t)64 * K, &LA[0][0] + ldsOff + 8192);              \
    GLDS16(Ag + ko_ + (size_t)96 * K, &LA[0][0] + ldsOff + 12288);             \
    GLDS16(Bg + ko_,                  &LB[0][0] + ldsOff);                     \
    GLDS16(Bg + ko_ + (size_t)32 * K, &LB[0][0] + ldsOff + 4096);              \
    GLDS16(Bg + ko_ + (size_t)64 * K, &LB[0][0] + ldsOff + 8192);              \
    GLDS16(Bg + ko_ + (size_t)96 * K, &LB[0][0] + ldsOff + 12288);             \
  } while (0)

  // kk-sliced read+MFMA: operand live-set = 8 i32x4 (32 regs) per slice.
#define RD_K(kk) do {                                                          \
    _Pragma("unroll") for (int mi = 0; mi < 4; ++mi)                           \
      a[mi] = *(const i32x4*)                                                  \
          &LA[wm * 64 + mi * 16 + lr][((kk) * 64 + kg * 16) ^ swz];            \
    _Pragma("unroll") for (int ni = 0; ni < 4; ++ni)                           \
      b[ni] = *(const i32x4*)                                                  \
          &LB[wn * 64 + ni * 16 + lr][((kk) * 64 + kg * 16) ^ swz];            \
  } while (0)

#define MM_K() do {                                                            \
    _Pragma("unroll") for (int mi = 0; mi < 4; ++mi)                           \
    _Pragma("unroll") for (int ni = 0; ni < 4; ++ni)                           \
      acc[mi][ni] = __builtin_amdgcn_mfma_i32_16x16x64_i8(                     \
          a[mi], b[ni], acc[mi][ni], 0, 0, 0);                                 \
  } while (0)

  i32x4 acc[4][4] = {};
  i32x4 a[4];
  i32x4 b[4];

  for (int tt = 0; tt < NT; ++tt) {
    STG_T(tt);
    asm volatile("s_waitcnt vmcnt(0)" ::: "memory");  // our stages landed
    __builtin_amdgcn_s_barrier();                     // everyone's landed
    RD_K(0);
    MM_K();
    __builtin_amdgcn_sched_barrier(0);  // fence: slice 2 reads may not hoist
    RD_K(1);
    MM_K();
    __builtin_amdgcn_sched_barrier(0);  // fence: next-tile stage may not sink in
    __builtin_amdgcn_s_barrier();                     // all reads retired
  }

  // epilogue
  int orow = m0 + wm * 64;
  int ocol = n0 + wn * 64;
  #pragma unroll
  for (int mf = 0; mf < 4; ++mf) {
    #pragma unroll
    for (int nf = 0; nf < 4; ++nf) {
      int col = ocol + nf * 16 + lr;
      float cs = __uint_as_float(colU[col]) * (1.f / 127.f);
      float bz = (EPI == 0 || ks == 0) ? bias[col] : 0.f;
      #pragma unroll
      for (int j = 0; j < 4; ++j) {
        int row = orow + mf * 16 + kg * 4 + j;   // C/D: col=lane&15, row=(lane>>4)*4+j
        float rs = (EPI == 0) ? rowS[row] : rowConst;
        float val = (float)acc[mf][nf][j] * rs * cs + bz;
        if (EPI == 0) {
          // tanh-approx GELU, then quantize to i8 act
          float u = val * (0.7978845608f + 0.0356774081f * val * val);
          float e = __expf(2.f * u);
          float th = 1.f - 2.f / (e + 1.f);
          val = 0.5f * val * (1.f + th);
          Cq[(size_t)row * N + col] = qclamp(val * ACT_INV);
        } else if (KS == 1) {
          size_t idx = (size_t)row * N + col;
          Cf[idx] = Cf[idx] + val;               // single writer per element
        } else {
          atomicAdd(&Cf[(size_t)row * N + col], val);  // split-K accumulate
        }
      }
    }
  }
#undef STG_T
#undef RD_K
#undef MM_K
}

extern "C" void kernel_launch(void* const* d_in, const int* in_sizes, int n_in,
                              void* d_out, int out_size, void* d_ws, size_t ws_size,
                              hipStream_t stream) {
  const float* x    = (const float*)d_in[0];
  // d_in[1]=wq, d_in[2]=wk are dead: attention mask keeps only key 0 ->
  // softmax is exactly onehot regardless of scores.
  const float* wv   = (const float*)d_in[3];
  const float* wo   = (const float*)d_in[4];
  const float* w1   = (const float*)d_in[5];
  const float* b1   = (const float*)d_in[6];
  const float* w2   = (const float*)d_in[7];
  const float* b2   = (const float*)d_in[8];
  const float* ln1a = (const float*)d_in[9];
  const float* ln1b = (const float*)d_in[10];
  const float* ln2a = (const float*)d_in[11];
  const float* ln2b = (const float*)d_in[12];
  float* out = (float*)d_out;

  char* ws = (char*)d_ws;
  signed char* w1t = (signed char*)(ws);                    // 4 MB [4096][1024] i8
  signed char* w2t = (signed char*)(ws + (4ull  << 20));    // 4 MB [1024][4096] i8
  signed char* h2  = (signed char*)(ws + (8ull  << 20));    // 8 MB [8192][1024] i8
  signed char* act = (signed char*)(ws + (16ull << 20));    // 32 MB [8192][4096] i8
  char* sc = ws + (48ull << 20);
  // zero-init region (one memset): u1|u2|v0|delta = 16K+4K+16K+16K = 52 KB
  unsigned* u1    = (unsigned*)(sc);                         // 4096 u32
  unsigned* u2    = (unsigned*)(sc + 16384);                 // 1024 u32
  float*    v0    = (float*)(sc + 20480);                    // [4][1024]
  float*    delta = (float*)(sc + 36864);                    // [4][1024]
  float*    hsc   = (float*)(sc + 53248);                    // [8192] row scales

  // 0) one memset for all accumulators/absmax buffers
  hipMemsetAsync(sc, 0, 53248, stream);

  // 1) weight quantization: per-col absmax -> transpose+quant i8 (inv inline)
  absmax_cols<<<dim3(HIDDEN / 256, D_MODEL / 64), 256, 0, stream>>>(w1, D_MODEL, HIDDEN, u1);
  absmax_cols<<<dim3(D_MODEL / 256, HIDDEN / 64), 256, 0, stream>>>(w2, HIDDEN, D_MODEL, u2);
  transpose_quant<<<dim3(HIDDEN / 32, D_MODEL / 32), 256, 0, stream>>>(w1, w1t, D_MODEL, HIDDEN, u1);
  transpose_quant<<<dim3(D_MODEL / 32, HIDDEN / 32), 256, 0, stream>>>(w2, w2t, HIDDEN, D_MODEL, u2);

  // 2) attention collapsed path (fp32 exact): LN1 fused into matvec1
  ln_matvec_split<<<dim3(D_MODEL / 256, KCHUNKS), 256, 0, stream>>>(
      x, ln1a, ln1b, wv, v0);                                   // v0 = LN1(x0) @ wv
  matvec_split_atomic<<<dim3(D_MODEL / 256, KCHUNKS), 256, 0, stream>>>(
      v0, wo, delta);                                           // delta = v0 @ wo

  // 3) x1 = x + delta[b] -> out (f32); h2 = quant(LN2(x1)) i8 + per-row scale
  fused_res_ln_q<<<NROWS, 256, 0, stream>>>(x, delta, ln2a, ln2b, out, h2, hsc);

  // 4) act = q8(gelu(h2 @ w1 + b1))  [8192 x 4096], 2048 blocks, MW=4 (A/B arm)
  gemm_i8<0, 1, 4><<<(NROWS / 128) * (HIDDEN / 128), 256, 0, stream>>>(
      h2, w1t, hsc, 0.f, u1, b1, act, nullptr, NROWS, HIDDEN, D_MODEL);

  // 5) out += act @ w2 + b2  [8192 x 1024], split-K=2, 1024 blocks, MW=3 (proven)
  gemm_i8<1, 2, 3><<<(NROWS / 128) * (D_MODEL / 128) * 2, 256, 0, stream>>>(
      act, w2t, nullptr, ACT_S, u2, b2, nullptr, out, NROWS, D_MODEL, HIDDEN);
}

// Round 14
// 201.423 us; speedup vs baseline: 1.0005x; 1.0005x over previous
//
#include <hip/hip_runtime.h>
#include <cstdint>

#define D_MODEL 1024
#define HIDDEN  4096
#define BATCH   4
#define SEQ     2048
#define NROWS   (BATCH*SEQ)   // 8192

typedef __attribute__((ext_vector_type(4))) int i32x4;

#define ACT_AMAX 4.0f
#define ACT_S    (ACT_AMAX / 127.0f)
#define ACT_INV  (127.0f / ACT_AMAX)

#define GLDS16(g, l) __builtin_amdgcn_global_load_lds(                        \
    (const __attribute__((address_space(1))) unsigned int*)(g),               \
    (__attribute__((address_space(3))) unsigned int*)(l), 16, 0, 0)

__device__ __forceinline__ float block_sum(float v, float* s4) {
  #pragma unroll
  for (int off = 32; off > 0; off >>= 1) v += __shfl_down(v, off);
  int lane = threadIdx.x & 63, wid = threadIdx.x >> 6;
  __syncthreads();
  if (lane == 0) s4[wid] = v;
  __syncthreads();
  return s4[0] + s4[1] + s4[2] + s4[3];
}

__device__ __forceinline__ float block_max(float v, float* s4) {
  #pragma unroll
  for (int off = 32; off > 0; off >>= 1) v = fmaxf(v, __shfl_down(v, off));
  int lane = threadIdx.x & 63, wid = threadIdx.x >> 6;
  __syncthreads();
  if (lane == 0) s4[wid] = v;
  __syncthreads();
  return fmaxf(fmaxf(s4[0], s4[1]), fmaxf(s4[2], s4[3]));
}

__device__ __forceinline__ signed char qclamp(float v) {
  float r = rintf(v);
  r = fminf(127.f, fmaxf(-127.f, r));
  return (signed char)(int)r;
}

// ---- per-column absmax of W [R][C] -> u32-encoded f32 maxima ----
__global__ __launch_bounds__(256) void absmax_cols(
    const float* __restrict__ in, int R, int C, unsigned* __restrict__ u) {
  int c  = blockIdx.x * 256 + threadIdx.x;
  int r0 = blockIdx.y * 64;
  float m = 0.f;
  #pragma unroll 4
  for (int r = 0; r < 64; ++r)
    m = fmaxf(m, fabsf(in[(size_t)(r0 + r) * C + c]));
  atomicMax(&u[c], __float_as_uint(m));   // non-negative f32: uint order == f32 order
}

// ---- transpose + quantize: in [R][C] f32 -> out [C][R] i8; inv from u32 absmax ----
__global__ __launch_bounds__(256) void transpose_quant(
    const float* __restrict__ in, signed char* __restrict__ out,
    int R, int C, const unsigned* __restrict__ u) {
  __shared__ float tile[32][33];
  int c0 = blockIdx.x * 32, r0 = blockIdx.y * 32;
  int tx = threadIdx.x & 31, ty = threadIdx.x >> 5;
  #pragma unroll
  for (int i = ty; i < 32; i += 8)
    tile[i][tx] = in[(size_t)(r0 + i) * C + c0 + tx];
  __syncthreads();
  #pragma unroll
  for (int i = ty; i < 32; i += 8) {
    float f = __uint_as_float(u[c0 + i]);
    float inv = f > 0.f ? 127.f / f : 0.f;
    out[(size_t)(c0 + i) * R + r0 + tx] = qclamp(tile[tx][i] * inv);
  }
}

// ---- fused LN1(row0 of each batch) + split-K matvec; atomicAdd into vout ----
#define KCHUNKS 32
#define KCH     (D_MODEL / KCHUNKS)   // 32
__global__ __launch_bounds__(256) void ln_matvec_split(
    const float* __restrict__ x, const float* __restrict__ ln_a,
    const float* __restrict__ ln_b, const float* __restrict__ W,
    float* __restrict__ vout) {
  __shared__ float s4[4];
  __shared__ float hs[4][KCH];
  int n  = blockIdx.x * 256 + threadIdx.x;
  int k0 = blockIdx.y * KCH;
  int t  = threadIdx.x;
  float4 g4 = ((const float4*)ln_a)[t];
  float4 b4 = ((const float4*)ln_b)[t];
  #pragma unroll
  for (int b = 0; b < 4; ++b) {
    const float* xr = x + (size_t)b * SEQ * D_MODEL;
    float4 v = ((const float4*)xr)[t];          // cols 4t..4t+3
    float sum = v.x + v.y + v.z + v.w;
    float mean = block_sum(sum, s4) * (1.f / 1024.f);
    float cx = v.x - mean, cy = v.y - mean, cz = v.z - mean, cw = v.w - mean;
    float sq = cx * cx + cy * cy + cz * cz + cw * cw;
    float var = block_sum(sq, s4) * (1.f / 1023.f);   // ddof=1
    float inv = 1.f / (sqrtf(var) + 1e-6f);           // eps on std
    if (t >= (k0 >> 2) && t < ((k0 + KCH) >> 2)) {    // keep our k-chunk
      int lc = 4 * t - k0;
      hs[b][lc + 0] = g4.x * cx * inv + b4.x;
      hs[b][lc + 1] = g4.y * cy * inv + b4.y;
      hs[b][lc + 2] = g4.z * cz * inv + b4.z;
      hs[b][lc + 3] = g4.w * cw * inv + b4.w;
    }
  }
  __syncthreads();
  float a0 = 0, a1 = 0, a2 = 0, a3 = 0;
  #pragma unroll
  for (int k = 0; k < KCH; ++k) {
    float w = W[(size_t)(k0 + k) * D_MODEL + n];
    a0 = fmaf(hs[0][k], w, a0);
    a1 = fmaf(hs[1][k], w, a1);
    a2 = fmaf(hs[2][k], w, a2);
    a3 = fmaf(hs[3][k], w, a3);
  }
  atomicAdd(&vout[0 * D_MODEL + n], a0);
  atomicAdd(&vout[1 * D_MODEL + n], a1);
  atomicAdd(&vout[2 * D_MODEL + n], a2);
  atomicAdd(&vout[3 * D_MODEL + n], a3);
}

// ---- split-K matvec (vin [4][D] dense), atomicAdd into vout ----
__global__ __launch_bounds__(256) void matvec_split_atomic(
    const float* __restrict__ vin, const float* __restrict__ W,
    float* __restrict__ vout) {
  __shared__ float hs[4][KCH];
  int n  = blockIdx.x * 256 + threadIdx.x;
  int k0 = blockIdx.y * KCH;
  if (threadIdx.x < 4 * KCH)
    hs[threadIdx.x / KCH][threadIdx.x % KCH] =
        vin[(threadIdx.x / KCH) * D_MODEL + k0 + (threadIdx.x % KCH)];
  __syncthreads();
  float a0 = 0, a1 = 0, a2 = 0, a3 = 0;
  #pragma unroll
  for (int k = 0; k < KCH; ++k) {
    float w = W[(size_t)(k0 + k) * D_MODEL + n];
    a0 = fmaf(hs[0][k], w, a0);
    a1 = fmaf(hs[1][k], w, a1);
    a2 = fmaf(hs[2][k], w, a2);
    a3 = fmaf(hs[3][k], w, a3);
  }
  atomicAdd(&vout[0 * D_MODEL + n], a0);
  atomicAdd(&vout[1 * D_MODEL + n], a1);
  atomicAdd(&vout[2 * D_MODEL + n], a2);
  atomicAdd(&vout[3 * D_MODEL + n], a3);
}

// ---- x1 = x + delta[b] -> out (f32); LN2 -> h2 (i8, per-row scale hs) ----
__global__ __launch_bounds__(256) void fused_res_ln_q(
    const float* __restrict__ x, const float* __restrict__ delta,
    const float* __restrict__ g, const float* __restrict__ be,
    float* __restrict__ x1_out, signed char* __restrict__ h2,
    float* __restrict__ hscale) {
  __shared__ float s4[4];
  int row = blockIdx.x;
  int b = row >> 11;                 // row / SEQ
  int t = threadIdx.x;
  float4 v  = ((const float4*)(x + (size_t)row * D_MODEL))[t];
  float4 d4 = ((const float4*)(delta + (size_t)b * D_MODEL))[t];
  v.x += d4.x; v.y += d4.y; v.z += d4.z; v.w += d4.w;
  float sum = v.x + v.y + v.z + v.w;
  float mean = block_sum(sum, s4) * (1.f / 1024.f);
  float cx = v.x - mean, cy = v.y - mean, cz = v.z - mean, cw = v.w - mean;
  float sq = cx * cx + cy * cy + cz * cz + cw * cw;
  float var = block_sum(sq, s4) * (1.f / 1023.f);   // ddof=1
  float inv = 1.f / (sqrtf(var) + 1e-6f);           // eps on std
  ((float4*)(x1_out + (size_t)row * D_MODEL))[t] = v;
  float4 g4 = ((const float4*)g)[t];
  float4 b4 = ((const float4*)be)[t];
  float h0v = g4.x * cx * inv + b4.x;
  float h1v = g4.y * cy * inv + b4.y;
  float h2v = g4.z * cz * inv + b4.z;
  float h3v = g4.w * cw * inv + b4.w;
  float am = fmaxf(fmaxf(fabsf(h0v), fabsf(h1v)), fmaxf(fabsf(h2v), fabsf(h3v)));
  float amax = block_max(am, s4);
  float qs = amax > 0.f ? 127.f / amax : 0.f;
  unsigned q = ((unsigned)(unsigned char)(int)qclamp(h0v * qs)) |
               ((unsigned)(unsigned char)(int)qclamp(h1v * qs) << 8) |
               ((unsigned)(unsigned char)(int)qclamp(h2v * qs) << 16) |
               ((unsigned)(unsigned char)(int)qclamp(h3v * qs) << 24);
  ((unsigned*)(h2 + (size_t)row * D_MODEL))[t] = q;
  if (t == 0) hscale[row] = amax * (1.f / 127.f);
}

// ============================================================================
// int8 128x128-tile GEMM, K-step 128, mfma_i32_16x16x64_i8, 4 waves (2Mx2N),
// 256 thr, single 32 KB LDS buffer, __launch_bounds__(256,3) -> 3 blocks/CU.
// R13 CONSOLIDATION: exact R9-proven inner structure (combined RD_AB, no
// sched fences), both template instantiations at MW=3 (R11/R12 showed a
// co-compiled MW=4 instance drags both to the spilled 60-VGPR codegen —
// rule #19; all-MW=3 builds get VGPR=64, no spill, 62.5 us/GEMM).
// 4-blocks/CU avenue CLOSED (R10/R11/R12 tripwires: spill every time).
// Per tile: {STG (8 gload_lds) -> vmcnt(0) -> bar -> RD+MFMA -> bar}.
// LDS rows 128 B, source col pre-swizzled, reads XOR (lr&7)<<4 -> 0 conflicts.
// EPI 0: dequant+bias+gelu -> i8 act.
// EPI 1: dequant(+bias if ks==0) -> add into Cf (KS=1: plain RMW; KS>1: atomic).
// ============================================================================
template <int EPI, int KS>
__global__ __launch_bounds__(256, 3) void gemm_i8(
    const signed char* __restrict__ A, const signed char* __restrict__ Bt,
    const float* __restrict__ rowS, float rowConst,
    const unsigned* __restrict__ colU, const float* __restrict__ bias,
    signed char* __restrict__ Cq, float* __restrict__ Cf, int M, int N, int K) {
  __shared__ signed char LA[128][128];   // 16 KB
  __shared__ signed char LB[128][128];   // 16 KB

  int GN  = N / 128;
  int PS  = (M / 128) * GN;          // blocks per k-slice
  int nwg = PS * KS;
  int id  = blockIdx.x;
  int sw  = (id & 7) * (nwg >> 3) + (id >> 3);      // XCD-aware swizzle
  int ks  = sw / PS, rem = sw % PS;
  int by  = rem / GN, bx = rem % GN;
  int m0  = by * 128, n0 = bx * 128;
  int KSL = K / KS;                  // K per slice
  int k0s = ks * KSL;
  int NT  = KSL / 128;               // K-tiles (128 i8 per step)

  int t = threadIdx.x;
  int wid = t >> 6, lane = t & 63;
  int wm = wid >> 1, wn = wid & 1;   // wave grid 2M x 2N, 64x64 per wave
  int lr = lane & 15, kg = lane >> 4;
  int swz = (lr & 7) << 4;           // read-side XOR (bytes)

  // staging: row = t>>3 (8 thr x 16B = one 128B row), pre-swizzled source col
  int rS = t >> 3;                   // 0..31
  int cS = ((t & 7) ^ (rS & 7)) * 16;
  const signed char* Ag = A  + (size_t)(m0 + rS) * K + k0s + cS;
  const signed char* Bg = Bt + (size_t)(n0 + rS) * K + k0s + cS;
  int ldsOff = wid * 1024;           // wave-uniform; lane*16B added by HW

#define STG_T(T) do {                                                          \
    size_t ko_ = (size_t)(T) * 128;                                            \
    GLDS16(Ag + ko_,                  &LA[0][0] + ldsOff);                     \
    GLDS16(Ag + ko_ + (size_t)32 * K, &LA[0][0] + ldsOff + 4096);              \
    GLDS16(Ag + ko_ + (size_t)64 * K, &LA[0][0] + ldsOff + 8192);              \
    GLDS16(Ag + ko_ + (size_t)96 * K, &LA[0][0] + ldsOff + 12288);             \
    GLDS16(Bg + ko_,                  &LB[0][0] + ldsOff);                     \
    GLDS16(Bg + ko_ + (size_t)32 * K, &LB[0][0] + ldsOff + 4096);              \
    GLDS16(Bg + ko_ + (size_t)64 * K, &LB[0][0] + ldsOff + 8192);              \
    GLDS16(Bg + ko_ + (size_t)96 * K, &LB[0][0] + ldsOff + 12288);             \
  } while (0)

#define RD_AB() do {                                                           \
    _Pragma("unroll") for (int mi = 0; mi < 4; ++mi)                           \
    _Pragma("unroll") for (int kk = 0; kk < 2; ++kk)                           \
      a[mi][kk] = *(const i32x4*)                                              \
          &LA[wm * 64 + mi * 16 + lr][(kk * 64 + kg * 16) ^ swz];              \
    _Pragma("unroll") for (int ni = 0; ni < 4; ++ni)                           \
    _Pragma("unroll") for (int kk = 0; kk < 2; ++kk)                           \
      b[ni][kk] = *(const i32x4*)                                              \
          &LB[wn * 64 + ni * 16 + lr][(kk * 64 + kg * 16) ^ swz];              \
  } while (0)

#define MM_ALL() do {                                                          \
    _Pragma("unroll") for (int mi = 0; mi < 4; ++mi)                           \
    _Pragma("unroll") for (int ni = 0; ni < 4; ++ni)                           \
    _Pragma("unroll") for (int kk = 0; kk < 2; ++kk)                           \
      acc[mi][ni] = __builtin_amdgcn_mfma_i32_16x16x64_i8(                     \
          a[mi][kk], b[ni][kk], acc[mi][ni], 0, 0, 0);                         \
  } while (0)

  i32x4 acc[4][4] = {};
  i32x4 a[4][2];
  i32x4 b[4][2];

  for (int tt = 0; tt < NT; ++tt) {
    STG_T(tt);
    asm volatile("s_waitcnt vmcnt(0)" ::: "memory");  // our stages landed
    __builtin_amdgcn_s_barrier();                     // everyone's landed
    RD_AB();
    MM_ALL();
    __builtin_amdgcn_s_barrier();                     // all reads retired
  }

  // epilogue
  int orow = m0 + wm * 64;
  int ocol = n0 + wn * 64;
  #pragma unroll
  for (int mf = 0; mf < 4; ++mf) {
    #pragma unroll
    for (int nf = 0; nf < 4; ++nf) {
      int col = ocol + nf * 16 + lr;
      float cs = __uint_as_float(colU[col]) * (1.f / 127.f);
      float bz = (EPI == 0 || ks == 0) ? bias[col] : 0.f;
      #pragma unroll
      for (int j = 0; j < 4; ++j) {
        int row = orow + mf * 16 + kg * 4 + j;   // C/D: col=lane&15, row=(lane>>4)*4+j
        float rs = (EPI == 0) ? rowS[row] : rowConst;
        float val = (float)acc[mf][nf][j] * rs * cs + bz;
        if (EPI == 0) {
          // tanh-approx GELU, then quantize to i8 act
          float u = val * (0.7978845608f + 0.0356774081f * val * val);
          float e = __expf(2.f * u);
          float th = 1.f - 2.f / (e + 1.f);
          val = 0.5f * val * (1.f + th);
          Cq[(size_t)row * N + col] = qclamp(val * ACT_INV);
        } else if (KS == 1) {
          size_t idx = (size_t)row * N + col;
          Cf[idx] = Cf[idx] + val;               // single writer per element
        } else {
          atomicAdd(&Cf[(size_t)row * N + col], val);  // split-K accumulate
        }
      }
    }
  }
#undef STG_T
#undef RD_AB
#undef MM_ALL
}

extern "C" void kernel_launch(void* const* d_in, const int* in_sizes, int n_in,
                              void* d_out, int out_size, void* d_ws, size_t ws_size,
                              hipStream_t stream) {
  const float* x    = (const float*)d_in[0];
  // d_in[1]=wq, d_in[2]=wk are dead: attention mask keeps only key 0 ->
  // softmax is exactly onehot regardless of scores.
  const float* wv   = (const float*)d_in[3];
  const float* wo   = (const float*)d_in[4];
  const float* w1   = (const float*)d_in[5];
  const float* b1   = (const float*)d_in[6];
  const float* w2   = (const float*)d_in[7];
  const float* b2   = (const float*)d_in[8];
  const float* ln1a = (const float*)d_in[9];
  const float* ln1b = (const float*)d_in[10];
  const float* ln2a = (const float*)d_in[11];
  const float* ln2b = (const float*)d_in[12];
  float* out = (float*)d_out;

  char* ws = (char*)d_ws;
  signed char* w1t = (signed char*)(ws);                    // 4 MB [4096][1024] i8
  signed char* w2t = (signed char*)(ws + (4ull  << 20));    // 4 MB [1024][4096] i8
  signed char* h2  = (signed char*)(ws + (8ull  << 20));    // 8 MB [8192][1024] i8
  signed char* act = (signed char*)(ws + (16ull << 20));    // 32 MB [8192][4096] i8
  char* sc = ws + (48ull << 20);
  // zero-init region (one memset): u1|u2|v0|delta = 16K+4K+16K+16K = 52 KB
  unsigned* u1    = (unsigned*)(sc);                         // 4096 u32
  unsigned* u2    = (unsigned*)(sc + 16384);                 // 1024 u32
  float*    v0    = (float*)(sc + 20480);                    // [4][1024]
  float*    delta = (float*)(sc + 36864);                    // [4][1024]
  float*    hsc   = (float*)(sc + 53248);                    // [8192] row scales

  // 0) one memset for all accumulators/absmax buffers
  hipMemsetAsync(sc, 0, 53248, stream);

  // 1) weight quantization: per-col absmax -> transpose+quant i8 (inv inline)
  absmax_cols<<<dim3(HIDDEN / 256, D_MODEL / 64), 256, 0, stream>>>(w1, D_MODEL, HIDDEN, u1);
  absmax_cols<<<dim3(D_MODEL / 256, HIDDEN / 64), 256, 0, stream>>>(w2, HIDDEN, D_MODEL, u2);
  transpose_quant<<<dim3(HIDDEN / 32, D_MODEL / 32), 256, 0, stream>>>(w1, w1t, D_MODEL, HIDDEN, u1);
  transpose_quant<<<dim3(D_MODEL / 32, HIDDEN / 32), 256, 0, stream>>>(w2, w2t, HIDDEN, D_MODEL, u2);

  // 2) attention collapsed path (fp32 exact): LN1 fused into matvec1
  ln_matvec_split<<<dim3(D_MODEL / 256, KCHUNKS), 256, 0, stream>>>(
      x, ln1a, ln1b, wv, v0);                                   // v0 = LN1(x0) @ wv
  matvec_split_atomic<<<dim3(D_MODEL / 256, KCHUNKS), 256, 0, stream>>>(
      v0, wo, delta);                                           // delta = v0 @ wo

  // 3) x1 = x + delta[b] -> out (f32); h2 = quant(LN2(x1)) i8 + per-row scale
  fused_res_ln_q<<<NROWS, 256, 0, stream>>>(x, delta, ln2a, ln2b, out, h2, hsc);

  // 4) act = q8(gelu(h2 @ w1 + b1))   [8192 x 4096], 2048 blocks, NT=8
  gemm_i8<0, 1><<<(NROWS / 128) * (HIDDEN / 128), 256, 0, stream>>>(
      h2, w1t, hsc, 0.f, u1, b1, act, nullptr, NROWS, HIDDEN, D_MODEL);

  // 5) out += act @ w2 + b2   [8192 x 1024], split-K=2, 1024 blocks, NT=16
  gemm_i8<1, 2><<<(NROWS / 128) * (D_MODEL / 128) * 2, 256, 0, stream>>>(
      act, w2t, nullptr, ACT_S, u2, b2, nullptr, out, NROWS, D_MODEL, HIDDEN);
}

// Round 15
// 183.458 us; speedup vs baseline: 1.0985x; 1.0979x over previous
//
#include <hip/hip_runtime.h>
#include <cstdint>

#define D_MODEL 1024
#define HIDDEN  4096
#define BATCH   4
#define SEQ     2048
#define NROWS   (BATCH*SEQ)   // 8192

typedef __attribute__((ext_vector_type(4))) int i32x4;

#define ACT_AMAX 4.0f
#define ACT_S    (ACT_AMAX / 127.0f)
#define ACT_INV  (127.0f / ACT_AMAX)

#define GLDS16(g, l) __builtin_amdgcn_global_load_lds(                        \
    (const __attribute__((address_space(1))) unsigned int*)(g),               \
    (__attribute__((address_space(3))) unsigned int*)(l), 16, 0, 0)

__device__ __forceinline__ float block_sum(float v, float* s4) {
  #pragma unroll
  for (int off = 32; off > 0; off >>= 1) v += __shfl_down(v, off);
  int lane = threadIdx.x & 63, wid = threadIdx.x >> 6;
  __syncthreads();
  if (lane == 0) s4[wid] = v;
  __syncthreads();
  return s4[0] + s4[1] + s4[2] + s4[3];
}

__device__ __forceinline__ float block_max(float v, float* s4) {
  #pragma unroll
  for (int off = 32; off > 0; off >>= 1) v = fmaxf(v, __shfl_down(v, off));
  int lane = threadIdx.x & 63, wid = threadIdx.x >> 6;
  __syncthreads();
  if (lane == 0) s4[wid] = v;
  __syncthreads();
  return fmaxf(fmaxf(s4[0], s4[1]), fmaxf(s4[2], s4[3]));
}

__device__ __forceinline__ signed char qclamp(float v) {
  float r = rintf(v);
  r = fminf(127.f, fmaxf(-127.f, r));
  return (signed char)(int)r;
}

// ---- per-column absmax of W [R][C] -> u32-encoded f32 maxima ----
__global__ __launch_bounds__(256) void absmax_cols(
    const float* __restrict__ in, int R, int C, unsigned* __restrict__ u) {
  int c  = blockIdx.x * 256 + threadIdx.x;
  int r0 = blockIdx.y * 64;
  float m = 0.f;
  #pragma unroll 4
  for (int r = 0; r < 64; ++r)
    m = fmaxf(m, fabsf(in[(size_t)(r0 + r) * C + c]));
  atomicMax(&u[c], __float_as_uint(m));   // non-negative f32: uint order == f32 order
}

// ---- transpose + quantize: in [R][C] f32 -> out [C][R] i8; inv from u32 absmax ----
__global__ __launch_bounds__(256) void transpose_quant(
    const float* __restrict__ in, signed char* __restrict__ out,
    int R, int C, const unsigned* __restrict__ u) {
  __shared__ float tile[32][33];
  int c0 = blockIdx.x * 32, r0 = blockIdx.y * 32;
  int tx = threadIdx.x & 31, ty = threadIdx.x >> 5;
  #pragma unroll
  for (int i = ty; i < 32; i += 8)
    tile[i][tx] = in[(size_t)(r0 + i) * C + c0 + tx];
  __syncthreads();
  #pragma unroll
  for (int i = ty; i < 32; i += 8) {
    float f = __uint_as_float(u[c0 + i]);
    float inv = f > 0.f ? 127.f / f : 0.f;
    out[(size_t)(c0 + i) * R + r0 + tx] = qclamp(tile[tx][i] * inv);
  }
}

// ---- fused LN1(row0 of each batch) + split-K matvec; atomicAdd into vout ----
#define KCHUNKS 32
#define KCH     (D_MODEL / KCHUNKS)   // 32
__global__ __launch_bounds__(256) void ln_matvec_split(
    const float* __restrict__ x, const float* __restrict__ ln_a,
    const float* __restrict__ ln_b, const float* __restrict__ W,
    float* __restrict__ vout) {
  __shared__ float s4[4];
  __shared__ float hs[4][KCH];
  int n  = blockIdx.x * 256 + threadIdx.x;
  int k0 = blockIdx.y * KCH;
  int t  = threadIdx.x;
  float4 g4 = ((const float4*)ln_a)[t];
  float4 b4 = ((const float4*)ln_b)[t];
  #pragma unroll
  for (int b = 0; b < 4; ++b) {
    const float* xr = x + (size_t)b * SEQ * D_MODEL;
    float4 v = ((const float4*)xr)[t];          // cols 4t..4t+3
    float sum = v.x + v.y + v.z + v.w;
    float mean = block_sum(sum, s4) * (1.f / 1024.f);
    float cx = v.x - mean, cy = v.y - mean, cz = v.z - mean, cw = v.w - mean;
    float sq = cx * cx + cy * cy + cz * cz + cw * cw;
    float var = block_sum(sq, s4) * (1.f / 1023.f);   // ddof=1
    float inv = 1.f / (sqrtf(var) + 1e-6f);           // eps on std
    if (t >= (k0 >> 2) && t < ((k0 + KCH) >> 2)) {    // keep our k-chunk
      int lc = 4 * t - k0;
      hs[b][lc + 0] = g4.x * cx * inv + b4.x;
      hs[b][lc + 1] = g4.y * cy * inv + b4.y;
      hs[b][lc + 2] = g4.z * cz * inv + b4.z;
      hs[b][lc + 3] = g4.w * cw * inv + b4.w;
    }
  }
  __syncthreads();
  float a0 = 0, a1 = 0, a2 = 0, a3 = 0;
  #pragma unroll
  for (int k = 0; k < KCH; ++k) {
    float w = W[(size_t)(k0 + k) * D_MODEL + n];
    a0 = fmaf(hs[0][k], w, a0);
    a1 = fmaf(hs[1][k], w, a1);
    a2 = fmaf(hs[2][k], w, a2);
    a3 = fmaf(hs[3][k], w, a3);
  }
  atomicAdd(&vout[0 * D_MODEL + n], a0);
  atomicAdd(&vout[1 * D_MODEL + n], a1);
  atomicAdd(&vout[2 * D_MODEL + n], a2);
  atomicAdd(&vout[3 * D_MODEL + n], a3);
}

// ---- split-K matvec (vin [4][D] dense), atomicAdd into vout ----
__global__ __launch_bounds__(256) void matvec_split_atomic(
    const float* __restrict__ vin, const float* __restrict__ W,
    float* __restrict__ vout) {
  __shared__ float hs[4][KCH];
  int n  = blockIdx.x * 256 + threadIdx.x;
  int k0 = blockIdx.y * KCH;
  if (threadIdx.x < 4 * KCH)
    hs[threadIdx.x / KCH][threadIdx.x % KCH] =
        vin[(threadIdx.x / KCH) * D_MODEL + k0 + (threadIdx.x % KCH)];
  __syncthreads();
  float a0 = 0, a1 = 0, a2 = 0, a3 = 0;
  #pragma unroll
  for (int k = 0; k < KCH; ++k) {
    float w = W[(size_t)(k0 + k) * D_MODEL + n];
    a0 = fmaf(hs[0][k], w, a0);
    a1 = fmaf(hs[1][k], w, a1);
    a2 = fmaf(hs[2][k], w, a2);
    a3 = fmaf(hs[3][k], w, a3);
  }
  atomicAdd(&vout[0 * D_MODEL + n], a0);
  atomicAdd(&vout[1 * D_MODEL + n], a1);
  atomicAdd(&vout[2 * D_MODEL + n], a2);
  atomicAdd(&vout[3 * D_MODEL + n], a3);
}

// ---- x1 = x + delta[b] -> out (f32); LN2 -> h2 (i8, per-row scale hs) ----
__global__ __launch_bounds__(256) void fused_res_ln_q(
    const float* __restrict__ x, const float* __restrict__ delta,
    const float* __restrict__ g, const float* __restrict__ be,
    float* __restrict__ x1_out, signed char* __restrict__ h2,
    float* __restrict__ hscale) {
  __shared__ float s4[4];
  int row = blockIdx.x;
  int b = row >> 11;                 // row / SEQ
  int t = threadIdx.x;
  float4 v  = ((const float4*)(x + (size_t)row * D_MODEL))[t];
  float4 d4 = ((const float4*)(delta + (size_t)b * D_MODEL))[t];
  v.x += d4.x; v.y += d4.y; v.z += d4.z; v.w += d4.w;
  float sum = v.x + v.y + v.z + v.w;
  float mean = block_sum(sum, s4) * (1.f / 1024.f);
  float cx = v.x - mean, cy = v.y - mean, cz = v.z - mean, cw = v.w - mean;
  float sq = cx * cx + cy * cy + cz * cz + cw * cw;
  float var = block_sum(sq, s4) * (1.f / 1023.f);   // ddof=1
  float inv = 1.f / (sqrtf(var) + 1e-6f);           // eps on std
  ((float4*)(x1_out + (size_t)row * D_MODEL))[t] = v;
  float4 g4 = ((const float4*)g)[t];
  float4 b4 = ((const float4*)be)[t];
  float h0v = g4.x * cx * inv + b4.x;
  float h1v = g4.y * cy * inv + b4.y;
  float h2v = g4.z * cz * inv + b4.z;
  float h3v = g4.w * cw * inv + b4.w;
  float am = fmaxf(fmaxf(fabsf(h0v), fabsf(h1v)), fmaxf(fabsf(h2v), fabsf(h3v)));
  float amax = block_max(am, s4);
  float qs = amax > 0.f ? 127.f / amax : 0.f;
  unsigned q = ((unsigned)(unsigned char)(int)qclamp(h0v * qs)) |
               ((unsigned)(unsigned char)(int)qclamp(h1v * qs) << 8) |
               ((unsigned)(unsigned char)(int)qclamp(h2v * qs) << 16) |
               ((unsigned)(unsigned char)(int)qclamp(h3v * qs) << 24);
  ((unsigned*)(h2 + (size_t)row * D_MODEL))[t] = q;
  if (t == 0) hscale[row] = amax * (1.f / 127.f);
}

// ============================================================================
// int8 128x128-tile GEMM -- EXACT R9 source (measured: VGPR 64, no spill,
// 62.5 us/GEMM).  template<int EPI> ONLY: R10-R13 showed that adding a KS
// template param (runtime ks = sw/PS, k0s offset, atomicAdd branch in the
// co-compiled instantiation) perturbs regalloc to a spilled 60-VGPR codegen
// for ALL instantiations (rule #19); reverting MW alone (R13) did not fix it.
// K-step 128, mfma_i32_16x16x64_i8, 4 waves (2Mx2N), 256 thr, single 32 KB
// LDS buffer, __launch_bounds__(256,3) -> 3 blocks/CU spill-free.
// Per tile: {STG (8 gload_lds) -> vmcnt(0) -> bar -> RD+MFMA -> bar}.
// LDS rows 128 B, source col pre-swizzled, reads XOR (lr&7)<<4 -> 0 conflicts.
// EPI 0: dequant+bias+gelu -> i8 act.  EPI 1: dequant+bias -> Cf += val.
// ============================================================================
template <int EPI>
__global__ __launch_bounds__(256, 3) void gemm_i8(
    const signed char* __restrict__ A, const signed char* __restrict__ Bt,
    const float* __restrict__ rowS, float rowConst,
    const unsigned* __restrict__ colU, const float* __restrict__ bias,
    signed char* __restrict__ Cq, float* __restrict__ Cf, int M, int N, int K) {
  __shared__ signed char LA[128][128];   // 16 KB
  __shared__ signed char LB[128][128];   // 16 KB

  int GN  = N / 128;
  int nwg = (M / 128) * GN;
  int id  = blockIdx.x;
  int sw  = (id & 7) * (nwg >> 3) + (id >> 3);      // XCD-aware swizzle
  int by  = sw / GN, bx = sw % GN;
  int m0  = by * 128, n0 = bx * 128;
  int NT  = K / 128;                 // K-tiles (128 i8 per step)

  int t = threadIdx.x;
  int wid = t >> 6, lane = t & 63;
  int wm = wid >> 1, wn = wid & 1;   // wave grid 2M x 2N, 64x64 per wave
  int lr = lane & 15, kg = lane >> 4;
  int swz = (lr & 7) << 4;           // read-side XOR (bytes)

  // staging: row = t>>3 (8 thr x 16B = one 128B row), pre-swizzled source col
  int rS = t >> 3;                   // 0..31
  int cS = ((t & 7) ^ (rS & 7)) * 16;
  const signed char* Ag = A  + (size_t)(m0 + rS) * K + cS;
  const signed char* Bg = Bt + (size_t)(n0 + rS) * K + cS;
  int ldsOff = wid * 1024;           // wave-uniform; lane*16B added by HW

#define STG_T(T) do {                                                          \
    size_t ko_ = (size_t)(T) * 128;                                            \
    GLDS16(Ag + ko_,                  &LA[0][0] + ldsOff);                     \
    GLDS16(Ag + ko_ + (size_t)32 * K, &LA[0][0] + ldsOff + 4096);              \
    GLDS16(Ag + ko_ + (size_t)64 * K, &LA[0][0] + ldsOff + 8192);              \
    GLDS16(Ag + ko_ + (size_t)96 * K, &LA[0][0] + ldsOff + 12288);             \
    GLDS16(Bg + ko_,                  &LB[0][0] + ldsOff);                     \
    GLDS16(Bg + ko_ + (size_t)32 * K, &LB[0][0] + ldsOff + 4096);              \
    GLDS16(Bg + ko_ + (size_t)64 * K, &LB[0][0] + ldsOff + 8192);              \
    GLDS16(Bg + ko_ + (size_t)96 * K, &LB[0][0] + ldsOff + 12288);             \
  } while (0)

#define RD_AB() do {                                                           \
    _Pragma("unroll") for (int mi = 0; mi < 4; ++mi)                           \
    _Pragma("unroll") for (int kk = 0; kk < 2; ++kk)                           \
      a[mi][kk] = *(const i32x4*)                                              \
          &LA[wm * 64 + mi * 16 + lr][(kk * 64 + kg * 16) ^ swz];              \
    _Pragma("unroll") for (int ni = 0; ni < 4; ++ni)                           \
    _Pragma("unroll") for (int kk = 0; kk < 2; ++kk)                           \
      b[ni][kk] = *(const i32x4*)                                              \
          &LB[wn * 64 + ni * 16 + lr][(kk * 64 + kg * 16) ^ swz];              \
  } while (0)

#define MM_ALL() do {                                                          \
    _Pragma("unroll") for (int mi = 0; mi < 4; ++mi)                           \
    _Pragma("unroll") for (int ni = 0; ni < 4; ++ni)                           \
    _Pragma("unroll") for (int kk = 0; kk < 2; ++kk)                           \
      acc[mi][ni] = __builtin_amdgcn_mfma_i32_16x16x64_i8(                     \
          a[mi][kk], b[ni][kk], acc[mi][ni], 0, 0, 0);                         \
  } while (0)

  i32x4 acc[4][4] = {};
  i32x4 a[4][2];
  i32x4 b[4][2];

  for (int tt = 0; tt < NT; ++tt) {
    STG_T(tt);
    asm volatile("s_waitcnt vmcnt(0)" ::: "memory");  // our stages landed
    __builtin_amdgcn_s_barrier();                     // everyone's landed
    RD_AB();
    MM_ALL();
    __builtin_amdgcn_s_barrier();                     // all reads retired
  }

  // epilogue
  int orow = m0 + wm * 64;
  int ocol = n0 + wn * 64;
  #pragma unroll
  for (int mf = 0; mf < 4; ++mf) {
    #pragma unroll
    for (int nf = 0; nf < 4; ++nf) {
      int col = ocol + nf * 16 + lr;
      float cs = __uint_as_float(colU[col]) * (1.f / 127.f);
      float bz = bias[col];
      #pragma unroll
      for (int j = 0; j < 4; ++j) {
        int row = orow + mf * 16 + kg * 4 + j;   // C/D: col=lane&15, row=(lane>>4)*4+j
        float rs = (EPI == 0) ? rowS[row] : rowConst;
        float val = (float)acc[mf][nf][j] * rs * cs + bz;
        if (EPI == 0) {
          // tanh-approx GELU, then quantize to i8 act
          float u = val * (0.7978845608f + 0.0356774081f * val * val);
          float e = __expf(2.f * u);
          float th = 1.f - 2.f / (e + 1.f);
          val = 0.5f * val * (1.f + th);
          Cq[(size_t)row * N + col] = qclamp(val * ACT_INV);
        } else {
          size_t idx = (size_t)row * N + col;
          Cf[idx] = Cf[idx] + val;               // residual x1 already there
        }
      }
    }
  }
#undef STG_T
#undef RD_AB
#undef MM_ALL
}

extern "C" void kernel_launch(void* const* d_in, const int* in_sizes, int n_in,
                              void* d_out, int out_size, void* d_ws, size_t ws_size,
                              hipStream_t stream) {
  const float* x    = (const float*)d_in[0];
  // d_in[1]=wq, d_in[2]=wk are dead: attention mask keeps only key 0 ->
  // softmax is exactly onehot regardless of scores.
  const float* wv   = (const float*)d_in[3];
  const float* wo   = (const float*)d_in[4];
  const float* w1   = (const float*)d_in[5];
  const float* b1   = (const float*)d_in[6];
  const float* w2   = (const float*)d_in[7];
  const float* b2   = (const float*)d_in[8];
  const float* ln1a = (const float*)d_in[9];
  const float* ln1b = (const float*)d_in[10];
  const float* ln2a = (const float*)d_in[11];
  const float* ln2b = (const float*)d_in[12];
  float* out = (float*)d_out;

  char* ws = (char*)d_ws;
  signed char* w1t = (signed char*)(ws);                    // 4 MB [4096][1024] i8
  signed char* w2t = (signed char*)(ws + (4ull  << 20));    // 4 MB [1024][4096] i8
  signed char* h2  = (signed char*)(ws + (8ull  << 20));    // 8 MB [8192][1024] i8
  signed char* act = (signed char*)(ws + (16ull << 20));    // 32 MB [8192][4096] i8
  char* sc = ws + (48ull << 20);
  // zero-init region (one memset): u1|u2|v0|delta = 16K+4K+16K+16K = 52 KB
  unsigned* u1    = (unsigned*)(sc);                         // 4096 u32
  unsigned* u2    = (unsigned*)(sc + 16384);                 // 1024 u32
  float*    v0    = (float*)(sc + 20480);                    // [4][1024]
  float*    delta = (float*)(sc + 36864);                    // [4][1024]
  float*    hsc   = (float*)(sc + 53248);                    // [8192] row scales

  // 0) one memset for all accumulators/absmax buffers
  hipMemsetAsync(sc, 0, 53248, stream);

  // 1) weight quantization: per-col absmax -> transpose+quant i8 (inv inline)
  absmax_cols<<<dim3(HIDDEN / 256, D_MODEL / 64), 256, 0, stream>>>(w1, D_MODEL, HIDDEN, u1);
  absmax_cols<<<dim3(D_MODEL / 256, HIDDEN / 64), 256, 0, stream>>>(w2, HIDDEN, D_MODEL, u2);
  transpose_quant<<<dim3(HIDDEN / 32, D_MODEL / 32), 256, 0, stream>>>(w1, w1t, D_MODEL, HIDDEN, u1);
  transpose_quant<<<dim3(D_MODEL / 32, HIDDEN / 32), 256, 0, stream>>>(w2, w2t, HIDDEN, D_MODEL, u2);

  // 2) attention collapsed path (fp32 exact): LN1 fused into matvec1
  ln_matvec_split<<<dim3(D_MODEL / 256, KCHUNKS), 256, 0, stream>>>(
      x, ln1a, ln1b, wv, v0);                                   // v0 = LN1(x0) @ wv
  matvec_split_atomic<<<dim3(D_MODEL / 256, KCHUNKS), 256, 0, stream>>>(
      v0, wo, delta);                                           // delta = v0 @ wo

  // 3) x1 = x + delta[b] -> out (f32); h2 = quant(LN2(x1)) i8 + per-row scale
  fused_res_ln_q<<<NROWS, 256, 0, stream>>>(x, delta, ln2a, ln2b, out, h2, hsc);

  // 4) act = q8(gelu(h2 @ w1 + b1))   [8192 x 4096], 2048 blocks, NT=8
  gemm_i8<0><<<(NROWS / 128) * (HIDDEN / 128), 256, 0, stream>>>(
      h2, w1t, hsc, 0.f, u1, b1, act, nullptr, NROWS, HIDDEN, D_MODEL);

  // 5) out += act @ w2 + b2          [8192 x 1024], 512 blocks, NT=32
  gemm_i8<1><<<(NROWS / 128) * (D_MODEL / 128), 256, 0, stream>>>(
      act, w2t, nullptr, ACT_S, u2, b2, nullptr, out, NROWS, D_MODEL, HIDDEN);
}